// Round 19
// baseline (810.813 us; speedup 1.0000x reference)
//
#include <hip/hip_runtime.h>
#include <hip/hip_bf16.h>
#include <math.h>

#define HW 65536L

typedef __attribute__((ext_vector_type(8))) short bf16x8;
typedef __attribute__((ext_vector_type(4))) float f32x4;

__device__ __forceinline__ int iabs_(int v) { return v < 0 ? -v : v; }

__device__ __forceinline__ void rtn_split(float f, unsigned short* h, unsigned short* l) {
  __hip_bfloat16 hb = __float2bfloat16(f);
  float hf = __bfloat162float(hb);
  __hip_bfloat16 lb = __float2bfloat16(f - hf);
  *h = *(unsigned short*)&hb;
  *l = *(unsigned short*)&lb;
}

// ---- split static 1x1 weights into (hi,lo) bf16 planes: whl[2][1152][96] ----
__global__ __launch_bounds__(256) void wsplit(
    const float* __restrict__ qk, const float* __restrict__ v,
    const float* __restrict__ q2, const float* __restrict__ k2,
    unsigned short* __restrict__ whl)
{
  const int e = blockIdx.x*256 + threadIdx.x;
  if (e >= 64512) return;
  const int row = e / 96, col = e - row*96;
  float f;
  if      (row <  192) f = qk[e];
  else if (row <  288) f = v [(row-192)*96+col];
  else if (row <  480) f = q2[(row-288)*96+col];
  else                 f = k2[(row-480)*96+col];
  rtn_split(f, &whl[e], &whl[110592 + e]);
}

// ---- compose CF = fqkv(288x96) @ proj(96x96) -> WHL rows 768..1055 ----
__global__ __launch_bounds__(256) void wcomp1(
    const float* __restrict__ fq, const float* __restrict__ pj,
    unsigned short* __restrict__ whl)
{
  const int e = blockIdx.x*256 + threadIdx.x;
  if (e >= 27648) return;
  const int row = e / 96, col = e - row*96;
  float s = 0.f;
  #pragma unroll 8
  for (int c = 0; c < 96; c++) s = fmaf(fq[row*96 + c], pj[c*96 + col], s);
  rtn_split(s, &whl[(768+row)*96 + col], &whl[110592 + (768+row)*96 + col]);
}

// ---- compose W2[b] = fproj(96x96) @ blockdiag(a2[b]) ----
__global__ __launch_bounds__(256) void wcomp2(
    const float* __restrict__ fp, const float* __restrict__ a2s,
    unsigned short* __restrict__ w2)
{
  const int e = blockIdx.x*256 + threadIdx.x;
  const int b = blockIdx.y;
  if (e >= 9216) return;
  const int co = e / 96, dg = e - co*96;
  const int h = dg / 12, d = dg - h*12;
  const float* ab = a2s + (((long)b*8 + h)*12)*12 + d;
  const float* fpb = fp + co*96 + h*12;
  float s = 0.f;
  #pragma unroll
  for (int c = 0; c < 12; c++) s = fmaf(fpb[c], ab[c*12], s);
  rtn_split(s, &w2[(long)b*9216 + e], &w2[18432 + (long)b*9216 + e]);
}

// ------- conv 1x1 via split-bf16 MFMA (3-way output split) -------
#define BLDS 104
__global__ __launch_bounds__(256) void conv1x1_mfma(
    const float* __restrict__ in, long in_bstride,
    const unsigned short* __restrict__ whl_hi, const unsigned short* __restrict__ whl_lo,
    long wbstride, int wrow0,
    float* __restrict__ out, long out_bstride,
    float* __restrict__ out2, long out2_bstride,
    float* __restrict__ out3, long out3_bstride,
    int ms1, int ms2, int mtiles, int mode)
{
  __shared__ unsigned short bhs[128*BLDS];
  __shared__ unsigned short bls[128*BLDS];
  const int t = threadIdx.x;
  const int p0 = blockIdx.x * 128;
  const int b = blockIdx.y;
  if (mode == 0) {
    #pragma unroll
    for (int it = 0; it < 6; it++) {
      const int idx = it*256 + t;
      const int g8 = idx >> 7;
      const int pix = idx & 127;
      const float* src = in + (long)b*in_bstride + (long)(g8*8)*HW + p0 + pix;
      unsigned hh[8], ll[8];
      #pragma unroll
      for (int j = 0; j < 8; j++) {
        float f = src[(long)j*HW];
        unsigned u = __float_as_uint(f);
        hh[j] = u >> 16;
        float lof = f - __uint_as_float(u & 0xFFFF0000u);
        __hip_bfloat16 lb = __float2bfloat16(lof);
        ll[j] = *(unsigned short*)&lb;
      }
      uint4 hv, lv;
      hv.x = hh[0]|(hh[1]<<16); hv.y = hh[2]|(hh[3]<<16);
      hv.z = hh[4]|(hh[5]<<16); hv.w = hh[6]|(hh[7]<<16);
      lv.x = ll[0]|(ll[1]<<16); lv.y = ll[2]|(ll[3]<<16);
      lv.z = ll[4]|(ll[5]<<16); lv.w = ll[6]|(ll[7]<<16);
      *(uint4*)(bhs + pix*BLDS + g8*8) = hv;
      *(uint4*)(bls + pix*BLDS + g8*8) = lv;
    }
  } else {
    const int pp = t >> 1, half = (t & 1)*48;
    const int p = p0 + pp;
    const int py = p >> 8, px = p & 255;
    const float* src = in + (long)b*in_bstride
        + ((long)((py & 63)*64 + (px & 63))*16 + ((py >> 6)*4 + (px >> 6)))*96 + half;
    #pragma unroll
    for (int j4 = 0; j4 < 12; j4++) {
      float4 v4 = *(const float4*)&src[j4*4];
      float fv[4] = {v4.x, v4.y, v4.z, v4.w};
      unsigned hh[4], ll[4];
      #pragma unroll
      for (int u4 = 0; u4 < 4; u4++) {
        unsigned u = __float_as_uint(fv[u4]);
        hh[u4] = u >> 16;
        float lof = fv[u4] - __uint_as_float(u & 0xFFFF0000u);
        __hip_bfloat16 lb = __float2bfloat16(lof);
        ll[u4] = *(unsigned short*)&lb;
      }
      uint2 hv, lv;
      hv.x = hh[0] | (hh[1] << 16); hv.y = hh[2] | (hh[3] << 16);
      lv.x = ll[0] | (ll[1] << 16); lv.y = ll[2] | (ll[3] << 16);
      *(uint2*)(bhs + pp*BLDS + half + j4*4) = hv;
      *(uint2*)(bls + pp*BLDS + half + j4*4) = lv;
    }
  }
  __syncthreads();
  const int lane = t & 63, w = t >> 6;
  const int fr = lane & 15, fk = lane >> 4;
  bf16x8 Bh[2][3], Bl[2][3];
  #pragma unroll
  for (int nt = 0; nt < 2; nt++)
    #pragma unroll
    for (int kt = 0; kt < 3; kt++) {
      const int pix = w*32 + nt*16 + fr;
      Bh[nt][kt] = *(const bf16x8*)(bhs + pix*BLDS + kt*32 + fk*8);
      Bl[nt][kt] = *(const bf16x8*)(bls + pix*BLDS + kt*32 + fk*8);
    }
  const long wb = (long)b*wbstride;
  for (int m = 0; m < mtiles; m++) {
    const long wbase = wb + (long)(wrow0 + m*16 + fr)*96 + fk*8;
    bf16x8 Ah[3], Al[3];
    #pragma unroll
    for (int kt = 0; kt < 3; kt++) {
      Ah[kt] = *(const bf16x8*)(whl_hi + wbase + kt*32);
      Al[kt] = *(const bf16x8*)(whl_lo + wbase + kt*32);
    }
    f32x4 acc[2] = {};
    #pragma unroll
    for (int nt = 0; nt < 2; nt++)
      #pragma unroll
      for (int kt = 0; kt < 3; kt++) {
        acc[nt] = __builtin_amdgcn_mfma_f32_16x16x32_bf16(Ah[kt], Bh[nt][kt], acc[nt], 0, 0, 0);
        acc[nt] = __builtin_amdgcn_mfma_f32_16x16x32_bf16(Ah[kt], Bl[nt][kt], acc[nt], 0, 0, 0);
        acc[nt] = __builtin_amdgcn_mfma_f32_16x16x32_bf16(Al[kt], Bh[nt][kt], acc[nt], 0, 0, 0);
      }
    int mo; float* dst;
    if (m < ms1)      { mo = m;       dst = out  + (long)b*out_bstride; }
    else if (m < ms2) { mo = m - ms1; dst = out2 + (long)b*out2_bstride; }
    else              { mo = m - ms2; dst = out3 + (long)b*out3_bstride; }
    dst += p0 + w*32;
    #pragma unroll
    for (int nt = 0; nt < 2; nt++)
      #pragma unroll
      for (int r = 0; r < 4; r++)
        dst[(long)(mo*16 + fk*4 + r)*HW + nt*16 + fr] = acc[nt][r];
  }
}

// -------- depthwise 3x3 pad 1, 4-wide vectorized --------
__global__ __launch_bounds__(256) void dw3x3v(
    const float* __restrict__ in, int inCH, const float* __restrict__ w,
    float* __restrict__ out, int outCH)
{
  const int t = threadIdx.x;
  const int p4 = blockIdx.x * 256 + t;
  const int ch = blockIdx.y, b = blockIdx.z;
  const int y = p4 >> 6, x0 = (p4 & 63) << 2;
  const float* ip = in + ((long)b*inCH + ch) * HW;
  const float* wp = w + ch*9;
  float a0 = 0.f, a1 = 0.f, a2 = 0.f, a3 = 0.f;
  #pragma unroll
  for (int dy = -1; dy <= 1; dy++) {
    const int yy = y + dy;
    if (yy < 0 || yy > 255) continue;
    const float* rp = ip + yy*256;
    const float4 c = *(const float4*)&rp[x0];
    const float left  = (x0 > 0)   ? rp[x0-1] : 0.f;
    const float right = (x0 < 252) ? rp[x0+4] : 0.f;
    const float w0 = wp[(dy+1)*3+0], w1 = wp[(dy+1)*3+1], w2 = wp[(dy+1)*3+2];
    a0 = fmaf(left, w0, a0); a0 = fmaf(c.x, w1, a0); a0 = fmaf(c.y, w2, a0);
    a1 = fmaf(c.x,  w0, a1); a1 = fmaf(c.y, w1, a1); a1 = fmaf(c.z, w2, a1);
    a2 = fmaf(c.y,  w0, a2); a2 = fmaf(c.z, w1, a2); a2 = fmaf(c.w, w2, a2);
    a3 = fmaf(c.z,  w0, a3); a3 = fmaf(c.w, w1, a3); a3 = fmaf(right, w2, a3);
  }
  float4 o; o.x = a0; o.y = a1; o.z = a2; o.w = a3;
  *(float4*)&out[((long)b*outCH + ch)*HW + y*256 + x0] = o;
}

// ------- depthwise 3x3 fused with v_s permutation (4-wide compute) ----
__global__ __launch_bounds__(256) void dw3x3_vs(
    const float* __restrict__ in, const float* __restrict__ w,
    float* __restrict__ vs)
{
  __shared__ float tile[96*65];
  const int t = threadIdx.x;
  const int gb = blockIdx.x;
  const int b = blockIdx.y;
  const int y = gb >> 2, xb = gb & 3;
  #pragma unroll
  for (int i = 0; i < 6; i++) {
    const int idx = i*256 + t;
    const int ci = idx >> 4, q = idx & 15;
    const int x0 = xb*64 + q*4;
    const float* ip = in + ((long)b*96 + ci) * HW;
    const float* wp = w + ci*9;
    float a0 = 0.f, a1 = 0.f, a2 = 0.f, a3 = 0.f;
    #pragma unroll
    for (int dy = -1; dy <= 1; dy++) {
      const int yy = y + dy;
      if (yy < 0 || yy > 255) continue;
      const float* rp = ip + yy*256;
      const float4 c = *(const float4*)&rp[x0];
      const float left  = (x0 > 0)   ? rp[x0-1] : 0.f;
      const float right = (x0 < 252) ? rp[x0+4] : 0.f;
      const float w0 = wp[(dy+1)*3+0], w1 = wp[(dy+1)*3+1], w2 = wp[(dy+1)*3+2];
      a0 = fmaf(left, w0, a0); a0 = fmaf(c.x, w1, a0); a0 = fmaf(c.y, w2, a0);
      a1 = fmaf(c.x,  w0, a1); a1 = fmaf(c.y, w1, a1); a1 = fmaf(c.z, w2, a1);
      a2 = fmaf(c.y,  w0, a2); a2 = fmaf(c.z, w1, a2); a2 = fmaf(c.w, w2, a2);
      a3 = fmaf(c.z,  w0, a3); a3 = fmaf(c.w, w1, a3); a3 = fmaf(right, w2, a3);
    }
    const int xl = q*4;
    tile[ci*65 + xl    ] = a0;
    tile[ci*65 + xl + 1] = a1;
    tile[ci*65 + xl + 2] = a2;
    tile[ci*65 + xl + 3] = a3;
  }
  __syncthreads();
  const int blk = (y >> 6)*4 + xb;
  float* obase = vs + ((long)b*4096 + (long)(y & 63)*64) * 1536 + blk*96;
  #pragma unroll
  for (int i = 0; i < 24; i++) {
    const int idx = i*256 + t;
    const int nl = idx / 96, ci = idx % 96;
    obase[(long)nl*1536 + ci] = tile[ci*65 + nl];
  }
}

// ---- depthwise 4x4 stride 4 pad 1 (256->64), 4-wide vectorized ----
__global__ __launch_bounds__(256) void dw4x4s4v(
    const float* __restrict__ in, const float* __restrict__ w,
    float* __restrict__ out)
{
  const int t = threadIdx.x;
  const int p = blockIdx.x*256 + t;
  const int ch = blockIdx.y, b = blockIdx.z;
  const int oy = p >> 4, qx = p & 15;
  const int x0 = qx*16;
  const float* ip = in + (long)(b*192 + ch) * HW;
  const float* wp = w + ch*16;
  float a0 = 0.f, a1 = 0.f, a2 = 0.f, a3 = 0.f;
  #pragma unroll
  for (int ty = 0; ty < 4; ty++) {
    const int iy = 4*oy + ty - 1;
    if (iy < 0 || iy > 255) continue;
    const float* rp = ip + iy*256;
    float r[17];
    r[0] = (x0 > 0) ? rp[x0-1] : 0.f;
    #pragma unroll
    for (int k = 0; k < 4; k++) {
      float4 v4 = *(const float4*)&rp[x0 + k*4];
      r[1+k*4+0]=v4.x; r[1+k*4+1]=v4.y; r[1+k*4+2]=v4.z; r[1+k*4+3]=v4.w;
    }
    const float w0=wp[ty*4+0], w1=wp[ty*4+1], w2=wp[ty*4+2], w3=wp[ty*4+3];
    a0=fmaf(r[ 0],w0,a0); a0=fmaf(r[ 1],w1,a0); a0=fmaf(r[ 2],w2,a0); a0=fmaf(r[ 3],w3,a0);
    a1=fmaf(r[ 4],w0,a1); a1=fmaf(r[ 5],w1,a1); a1=fmaf(r[ 6],w2,a1); a1=fmaf(r[ 7],w3,a1);
    a2=fmaf(r[ 8],w0,a2); a2=fmaf(r[ 9],w1,a2); a2=fmaf(r[10],w2,a2); a2=fmaf(r[11],w3,a2);
    a3=fmaf(r[12],w0,a3); a3=fmaf(r[13],w1,a3); a3=fmaf(r[14],w2,a3); a3=fmaf(r[15],w3,a3);
  }
  float4 o; o.x=a0; o.y=a1; o.z=a2; o.w=a3;
  *(float4*)&out[(long)(b*192 + ch)*4096 + oy*64 + qx*4] = o;
}

// ---------------- l2 norm over 192 channels + transpose (both q & k) ----
__global__ __launch_bounds__(256) void l2n192(
    const float* __restrict__ inA, float* __restrict__ outA,
    const float* __restrict__ inB, float* __restrict__ outB)
{
  const int t = threadIdx.x;
  const int wid = t >> 6, lane = t & 63;
  const int gw2 = blockIdx.x * 4 + wid;
  const int sel = gw2 >> 13;
  const int gw = gw2 & 8191;
  const int b = gw >> 12, n = gw & 4095;
  const float* ip = (sel ? inB : inA) + (long)b * 786432;
  float v0 = ip[(long)(lane      ) * 4096 + n];
  float v1 = ip[(long)(lane +  64) * 4096 + n];
  float v2 = ip[(long)(lane + 128) * 4096 + n];
  float ss = v0*v0 + v1*v1 + v2*v2;
  #pragma unroll
  for (int s = 1; s < 64; s <<= 1) ss += __shfl_xor(ss, s, 64);
  float nrm = fmaxf(sqrtf(ss), 1e-12f);
  float* op = (sel ? outB : outA) + ((long)b*4096 + n) * 192;
  op[lane      ] = v0 / nrm;
  op[lane +  64] = v1 / nrm;
  op[lane + 128] = v2 / nrm;
}

// ------- split fp32 -> (hi,lo) bf16 planes; both batches -------
__global__ __launch_bounds__(256) void bf16split(
    const float* __restrict__ in, unsigned short* __restrict__ outp)
{
  const int i = blockIdx.x * 256 + threadIdx.x;
  const int n = i / 192, k = i % 192;
  float f = in[i];
  unsigned short h, l;
  rtn_split(f, &h, &l);
  outp[(long)n*384 + k]       = h;
  outp[(long)n*384 + 192 + k] = l;
}

// ------- attention QK^T via split-bf16 MFMA (both batches) -------
#define LDSROW 40
__global__ __launch_bounds__(256) void attn_qk_mfma(
    const unsigned short* __restrict__ Qsp, const unsigned short* __restrict__ Ksp,
    float* __restrict__ attn, const float* __restrict__ tp)
{
  __shared__ unsigned short qs[256*LDSROW];
  __shared__ unsigned short ks[256*LDSROW];
  const int t = threadIdx.x;
  const int lane = t & 63, w = t >> 6;
  const int n0 = blockIdx.x * 128;
  const int m0 = blockIdx.y * 128;
  const int bb = blockIdx.z;
  const unsigned short* Qb = Qsp + (long)bb*1572864;
  const unsigned short* Kb = Ksp + (long)bb*1572864;
  float* attb = attn + (long)bb*16777216;
  const int wr = (w >> 1) * 64, wc = (w & 1) * 64;
  f32x4 acc[4][4] = {};
  const int srow = t & 127;
  const int shl  = t >> 7;
  const unsigned short* qsrc = Qb + (long)(n0 + srow) * 384 + shl * 192;
  const unsigned short* ksrc = Kb + (long)(m0 + srow) * 384 + shl * 192;
  unsigned short* qdst = qs + (shl*128 + srow) * LDSROW;
  unsigned short* kdst = ks + (shl*128 + srow) * LDSROW;
  const int fr = lane & 15;
  const int fk = lane >> 4;
  for (int s = 0; s < 6; s++) {
    __syncthreads();
    #pragma unroll
    for (int j = 0; j < 4; j++) {
      *(bf16x8*)(qdst + j*8) = *(const bf16x8*)(qsrc + s*32 + j*8);
      *(bf16x8*)(kdst + j*8) = *(const bf16x8*)(ksrc + s*32 + j*8);
    }
    __syncthreads();
    bf16x8 ah[4], al[4], bh[4], bl[4];
    #pragma unroll
    for (int i = 0; i < 4; i++) {
      ah[i] = *(const bf16x8*)(qs + (      wr + i*16 + fr) * LDSROW + fk*8);
      al[i] = *(const bf16x8*)(qs + (128 + wr + i*16 + fr) * LDSROW + fk*8);
      bh[i] = *(const bf16x8*)(ks + (      wc + i*16 + fr) * LDSROW + fk*8);
      bl[i] = *(const bf16x8*)(ks + (128 + wc + i*16 + fr) * LDSROW + fk*8);
    }
    #pragma unroll
    for (int i = 0; i < 4; i++)
      #pragma unroll
      for (int j = 0; j < 4; j++) {
        acc[i][j] = __builtin_amdgcn_mfma_f32_16x16x32_bf16(ah[i], bh[j], acc[i][j], 0, 0, 0);
        acc[i][j] = __builtin_amdgcn_mfma_f32_16x16x32_bf16(ah[i], bl[j], acc[i][j], 0, 0, 0);
        acc[i][j] = __builtin_amdgcn_mfma_f32_16x16x32_bf16(al[i], bh[j], acc[i][j], 0, 0, 0);
      }
  }
  const float temp = tp[0];
  #pragma unroll
  for (int i = 0; i < 4; i++)
    #pragma unroll
    for (int j = 0; j < 4; j++)
      #pragma unroll
      for (int r = 0; r < 4; r++) {
        const int nn = n0 + wr + i*16 + (lane >> 4)*4 + r;
        const int mm = m0 + wc + j*16 + (lane & 15);
        attb[(long)nn*4096 + mm] = acc[i][j][r] * temp;
      }
}

// ------- top-5 + local mask + softmax + sparse out -------
// R19: 384 threads; phases<=softmax on t<256; PV/store balanced 1 float4/thread.
#define CAP 128
__global__ __launch_bounds__(384) void attn_out_k(
    const float* __restrict__ attn, const float* __restrict__ vs,
    float* __restrict__ outr)
{
  __shared__ float top5[256*5];
  __shared__ int   lm[CAP];
  __shared__ float lw[CAP];
  __shared__ float ses[CAP];
  __shared__ float redf[8];
  __shared__ int   wsum[4];
  const int t = threadIdx.x;
  const int bid = blockIdx.x;
  const int n = ((bid & 7) << 9) | (bid >> 3);   // XCD-chunked rows
  const int bb = blockIdx.y;
  const float* ar = attn + (long)bb*16777216 + (long)n * 4096;
  const float* vsb = vs + (long)bb*6291456;
  float av[16];
  float fvv[16];
  const int y = n >> 6, x = n & 63;
  if (t < 256) {
    float t0=-INFINITY,t1=-INFINITY,t2=-INFINITY,t3=-INFINITY,t4=-INFINITY;
    #pragma unroll
    for (int q = 0; q < 4; q++) {
      float4 v4 = *(const float4*)&ar[t*16 + q*4];
      float vv[4] = {v4.x, v4.y, v4.z, v4.w};
      #pragma unroll
      for (int u = 0; u < 4; u++) {
        float v = vv[u];
        av[q*4+u] = v;
        if (v > t4) {
          if (v > t0)      { t4=t3; t3=t2; t2=t1; t1=t0; t0=v; }
          else if (v > t1) { t4=t3; t3=t2; t2=t1; t1=v; }
          else if (v > t2) { t4=t3; t3=t2; t2=v; }
          else if (v > t3) { t4=t3; t3=v; }
          else             { t4=v; }
        }
      }
    }
    top5[t*5+0]=t0; top5[t*5+1]=t1; top5[t*5+2]=t2; top5[t*5+3]=t3; top5[t*5+4]=t4;
  }
  __syncthreads();
  for (int s = 128; s >= 1; s >>= 1) {
    if (t < s) {
      float* A = &top5[t*5];
      const float* B = &top5[(t+s)*5];
      float m[5]; int i = 0, j = 0;
      #pragma unroll
      for (int k = 0; k < 5; k++) {
        float avv = A[i], bv = B[j];
        if (avv >= bv) { m[k] = avv; i++; } else { m[k] = bv; j++; }
      }
      #pragma unroll
      for (int k = 0; k < 5; k++) A[k] = m[k];
    }
    __syncthreads();
  }
  const float kth = top5[4];
  int myc = 0;
  float wmax = -INFINITY;
  if (t < 256) {
    #pragma unroll
    for (int k = 0; k < 16; k++) {
      const int m = t*16 + k;
      float a = av[k];
      int c = ((a >= kth) ? 1 : 0) +
              (((iabs_(y - (m >> 6)) + iabs_(x - (m & 63))) <= 4) ? 1 : 0);
      float wv = a * (float)c;
      fvv[k] = wv;
      if (wv != 0.0f) { myc++; wmax = fmaxf(wmax, wv); }
    }
    int inc = myc;
    #pragma unroll
    for (int s = 1; s < 64; s <<= 1) {
      int v = __shfl_up(inc, s, 64);
      if ((t & 63) >= s) inc += v;
    }
    if ((t & 63) == 63) wsum[t >> 6] = inc;
    // stash exclusive base in av[0]'s register slot via inc-myc later
    av[0] = __int_as_float(inc - myc);
  }
  __syncthreads();
  if (t < 256) {
    int pre = 0;
    #pragma unroll
    for (int wj = 0; wj < 4; wj++) pre += (wj < (t >> 6)) ? wsum[wj] : 0;
    int idx = pre + __float_as_int(av[0]);
    #pragma unroll
    for (int k = 0; k < 16; k++) {
      float wv = fvv[k];
      if (wv != 0.0f && idx < CAP) { lm[idx] = t*16 + k; lw[idx] = wv; idx++; }
    }
    #pragma unroll
    for (int s = 1; s < 64; s <<= 1) wmax = fmaxf(wmax, __shfl_xor(wmax, s, 64));
    if ((t & 63) == 0) redf[t >> 6] = wmax;
  }
  __syncthreads();
  const int cnt = wsum[0] + wsum[1] + wsum[2] + wsum[3];
  const float gmax = fmaxf(fmaxf(redf[0], redf[1]), fmaxf(redf[2], redf[3]));
  __syncthreads();
  if (t < CAP) ses[t] = (t < cnt) ? expf(lw[t] - gmax) : 0.f;
  __syncthreads();
  if (t < 256) {
    float ps = (t < cnt && t < CAP) ? ses[t] : 0.f;
    #pragma unroll
    for (int s = 1; s < 64; s <<= 1) ps += __shfl_xor(ps, s, 64);
    if ((t & 63) == 0) redf[4 + (t >> 6)] = ps;
  }
  __syncthreads();
  const float S = redf[4] + redf[5] + redf[6] + redf[7];
  const float invS = 1.0f / S;
  // PV: all 384 threads, exactly one float4 chain each (1536 = 384*4)
  float a0 = 0.f, a1 = 0.f, a2 = 0.f, a3 = 0.f;
  const int ecnt = (cnt < CAP) ? cnt : CAP;
  const float* vbase = vsb + t*4;
  for (int e = 0; e < ecnt; e++) {
    float se = ses[e];
    float4 v4 = *(const float4*)(vbase + (long)lm[e] * 1536);
    a0 = fmaf(se, v4.x, a0);
    a1 = fmaf(se, v4.y, a1);
    a2 = fmaf(se, v4.z, a2);
    a3 = fmaf(se, v4.w, a3);
  }
  float* orow = outr + (long)bb*6291456 + (long)n * 1536;
  float4 o; o.x = a0*invS; o.y = a1*invS; o.z = a2*invS; o.w = a3*invS;
  *(float4*)&orow[t*4] = o;
}

// ------- per-channel l2 norm over 65536 (fhr k2); in-place safe -------
__global__ __launch_bounds__(1024) void l2n_sp(
    const float* __restrict__ in, float* __restrict__ out)
{
  const int ch = blockIdx.x, b = blockIdx.y, t = threadIdx.x;
  const float* ip = in + ((long)b*96 + ch) * HW;
  float ss = 0.f;
  for (int i = t; i < 65536; i += 1024) { float v = ip[i]; ss = fmaf(v, v, ss); }
  __shared__ float red[16];
  #pragma unroll
  for (int s = 1; s < 64; s <<= 1) ss += __shfl_xor(ss, s, 64);
  if ((t & 63) == 0) red[t >> 6] = ss;
  __syncthreads();
  if (t == 0) {
    float s2 = 0.f;
    for (int i = 0; i < 16; i++) s2 += red[i];
    red[0] = fmaxf(sqrtf(s2), 1e-12f);
  }
  __syncthreads();
  const float nrm = red[0];
  float* op = out + ((long)b*96 + ch) * HW;
  for (int i = t; i < 65536; i += 1024) op[i] = ip[i] / nrm;
}

// -------- a2 stage 1: raw-q Gram + q sum-of-squares partials ----------
#define A2_NCH 16
__global__ __launch_bounds__(256) void a2_part(
    const float* __restrict__ q2n, const float* __restrict__ k2n,
    float* __restrict__ part, float* __restrict__ qqpart)
{
  __shared__ float sh[24*260];
  const int t = threadIdx.x;
  const int ch = blockIdx.x, h = blockIdx.y, b = blockIdx.z;
  const long base = ((long)b*96 + h*12) * HW + ch*4096;
  const int c = t / 12, d = t - (t/12)*12;
  float acc = 0.f;
  float qq = 0.f;
  for (int sub = 0; sub < 16; sub++) {
    __syncthreads();
    #pragma unroll
    for (int j = 0; j < 6; j++) {
      const int v = j*256 + t;
      const int row = v >> 6;
      const int col4 = v & 63;
      const float* src = (row < 12)
        ? q2n + base + (long)row*HW + sub*256 + col4*4
        : k2n + base + (long)(row-12)*HW + sub*256 + col4*4;
      *(float4*)&sh[row*260 + col4*4] = *(const float4*)src;
    }
    __syncthreads();
    if (t < 144) {
      const float* qr = &sh[c*260];
      const float* kr = &sh[(12+d)*260];
      #pragma unroll
      for (int i4 = 0; i4 < 64; i4++) {
        float4 qv = *(const float4*)&qr[i4*4];
        float4 kv = *(const float4*)&kr[i4*4];
        acc = fmaf(qv.x, kv.x, acc);
        acc = fmaf(qv.y, kv.y, acc);
        acc = fmaf(qv.z, kv.z, acc);
        acc = fmaf(qv.w, kv.w, acc);
      }
    } else if (t < 156) {
      const float* qr = &sh[(t-144)*260];
      #pragma unroll
      for (int i4 = 0; i4 < 64; i4++) {
        float4 qv = *(const float4*)&qr[i4*4];
        qq = fmaf(qv.x, qv.x, qq);
        qq = fmaf(qv.y, qv.y, qq);
        qq = fmaf(qv.z, qv.z, qq);
        qq = fmaf(qv.w, qv.w, qq);
      }
    }
  }
  if (t < 144)
    part[(((long)b*8 + h)*A2_NCH + ch)*144 + t] = acc;
  else if (t < 156)
    qqpart[(((long)b*8 + h)*A2_NCH + ch)*12 + (t-144)] = qq;
}

// -------- a2 stage 2: fold q-normalization --------
__global__ __launch_bounds__(256) void a2_fin(
    const float* __restrict__ part, const float* __restrict__ qqpart,
    const float* __restrict__ temp, float* __restrict__ a2s)
{
  __shared__ float m[144];
  __shared__ float qn[12];
  const int t = threadIdx.x;
  const int h = blockIdx.x, b = blockIdx.y;
  if (t < 144) {
    float s = 0.f;
    const float* pp = part + (((long)b*8 + h)*A2_NCH)*144 + t;
    #pragma unroll
    for (int ch = 0; ch < A2_NCH; ch++) s += pp[ch*144];
    m[t] = s;
  } else if (t < 156) {
    float s = 0.f;
    const float* pp = qqpart + (((long)b*8 + h)*A2_NCH)*12 + (t-144);
    #pragma unroll
    for (int ch = 0; ch < A2_NCH; ch++) s += pp[ch*12];
    qn[t-144] = fmaxf(sqrtf(s), 1e-12f);
  }
  __syncthreads();
  if (t < 12) {
    const float tv = temp[h];
    const float scale = tv / qn[t];
    float mx = -INFINITY;
    float a[12];
    #pragma unroll
    for (int d = 0; d < 12; d++) { a[d] = m[t*12+d] * scale; mx = fmaxf(mx, a[d]); }
    float e[12], sum = 0.f;
    #pragma unroll
    for (int d = 0; d < 12; d++) { e[d] = expf(a[d]-mx); sum += e[d]; }
    float inv = 1.0f/sum;
    float* op = a2s + (((long)b*8 + h)*12 + t)*12;
    #pragma unroll
    for (int d = 0; d < 12; d++) op[d] = e[d]*inv;
  }
}

extern "C" void kernel_launch(void* const* d_in, const int* in_sizes, int n_in,
                              void* d_out, int out_size, void* d_ws, size_t ws_size,
                              hipStream_t stream) {
  const float* x        = (const float*)d_in[0];
  const float* qk_w     = (const float*)d_in[1];
  const float* qk_dw    = (const float*)d_in[2];
  const float* v_w      = (const float*)d_in[3];
  const float* v_dw     = (const float*)d_in[4];
  const float* k2_w     = (const float*)d_in[5];
  const float* k2_dw    = (const float*)d_in[6];
  const float* q2_w     = (const float*)d_in[7];
  const float* q2_dw    = (const float*)d_in[8];
  const float* proj_w   = (const float*)d_in[9];
  const float* sab_temp = (const float*)d_in[10];
  const float* fqkv_w   = (const float*)d_in[11];
  const float* fqkv_dw  = (const float*)d_in[12];
  const float* fproj_w  = (const float*)d_in[13];
  const float* fhr_temp = (const float*)d_in[14];
  float* out = (float*)d_out;
  float* ws  = (float*)d_ws;

  float* O2  = out;
  float* KS  = out + 12582912;
  float* VS  = out + 14155776;
  float* K2N = out + 26738688;
  float* V2  = out + 39321600;

  float* A0   = ws;
  float* A1   = ws + 25165824;
  float* QD   = ws + 50331648;
  float* KD   = ws + 51904512;
  float* QN   = ws + 53477376;
  float* A2S  = ws + 55050240;
  float* PART = ws + 55052544;
  unsigned short* WHL = (unsigned short*)QN;
  float* ATT  = ws;
  unsigned short* QSP = (unsigned short*)(ws + 33554432);
  unsigned short* KSP = (unsigned short*)(ws + 35127296);
  float* AOUT = ws + 37748736;
  float* P1  = ws;
  float* P2  = ws + 12582912;
  float* P3  = ws + 25165824;
  float* ALNQ = P2;
  float* QQP = QD;
  unsigned short* W2HL = (unsigned short*)PART;

  dim3 b256(256), b384(384), b1024(1024);

  wsplit<<<dim3(252), b256, 0, stream>>>(qk_w, v_w, q2_w, k2_w, WHL);
  conv1x1_mfma<<<dim3(512,2), b256, 0, stream>>>(
      x, 96L*HW, WHL, WHL+110592, 0, 0,
      A0, 192L*HW, A1, 96L*HW, A1, 96L*HW, 12, 18, 18, 0);
  dw3x3_vs<<<dim3(1024,2), b256, 0, stream>>>(A1, v_dw, VS);
  dw3x3v<<<dim3(64,192,2), b256, 0, stream>>>(A0, 192, qk_dw, A1, 192);
  conv1x1_mfma<<<dim3(512,2), b256, 0, stream>>>(
      A1, 192L*HW, WHL, WHL+110592, 0, 288,
      A0, 192L*HW, A0, 192L*HW, A0, 192L*HW, 12, 12, 12, 0);
  dw4x4s4v<<<dim3(4,192,2), b256, 0, stream>>>(A0, q2_dw, QD);
  conv1x1_mfma<<<dim3(512,2), b256, 0, stream>>>(
      A1 + 96L*HW, 192L*HW, WHL, WHL+110592, 0, 480,
      A0, 192L*HW, A0, 192L*HW, A0, 192L*HW, 12, 12, 12, 0);
  dw4x4s4v<<<dim3(4,192,2), b256, 0, stream>>>(A0, k2_dw, KD);
  l2n192<<<dim3(4096), b256, 0, stream>>>(QD, QN, KD, KS);
  bf16split<<<dim3(6144), b256, 0, stream>>>(QN, QSP);
  bf16split<<<dim3(6144), b256, 0, stream>>>(KS, KSP);
  attn_qk_mfma<<<dim3(32,32,2), b256, 0, stream>>>(QSP, KSP, ATT, sab_temp);
  attn_out_k<<<dim3(4096,2), b384, 0, stream>>>(ATT, VS, AOUT);
  wcomp1<<<dim3(108), b256, 0, stream>>>(fqkv_w, proj_w, WHL);
  conv1x1_mfma<<<dim3(512,2), b256, 0, stream>>>(
      AOUT, 6291456L, WHL, WHL+110592, 0, 768,
      P1, 96L*HW, P2, 96L*HW, P3, 96L*HW, 6, 12, 18, 1);
  dw3x3v<<<dim3(64,96,2), b256, 0, stream>>>(P2, 96, fqkv_dw +  864, K2N, 96);
  dw3x3v<<<dim3(64,96,2), b256, 0, stream>>>(P3, 96, fqkv_dw + 1728, V2,  96);
  dw3x3v<<<dim3(64,96,2), b256, 0, stream>>>(P1, 96, fqkv_dw,        ALNQ, 96);
  l2n_sp<<<dim3(96,2), b1024, 0, stream>>>(K2N, K2N);
  a2_part<<<dim3(A2_NCH,8,2), b256, 0, stream>>>(ALNQ, K2N, PART, QQP);
  a2_fin<<<dim3(8,2), b256, 0, stream>>>(PART, QQP, fhr_temp, A2S);
  wcomp2<<<dim3(36,2), b256, 0, stream>>>(fproj_w, A2S, W2HL);
  conv1x1_mfma<<<dim3(512,2), b256, 0, stream>>>(
      V2, 96L*HW, W2HL, W2HL+18432, 9216, 0,
      O2, 96L*HW, O2, 96L*HW, O2, 96L*HW, 6, 6, 6, 0);
}

// Round 20
// 799.590 us; speedup vs baseline: 1.0140x; 1.0140x over previous
//
#include <hip/hip_runtime.h>
#include <hip/hip_bf16.h>
#include <math.h>

#define HW 65536L

typedef __attribute__((ext_vector_type(8))) short bf16x8;
typedef __attribute__((ext_vector_type(4))) float f32x4;

__device__ __forceinline__ int iabs_(int v) { return v < 0 ? -v : v; }

__device__ __forceinline__ void rtn_split(float f, unsigned short* h, unsigned short* l) {
  __hip_bfloat16 hb = __float2bfloat16(f);
  float hf = __bfloat162float(hb);
  __hip_bfloat16 lb = __float2bfloat16(f - hf);
  *h = *(unsigned short*)&hb;
  *l = *(unsigned short*)&lb;
}

// ---- split static 1x1 weights into (hi,lo) bf16 planes: whl[2][1152][96] ----
__global__ __launch_bounds__(256) void wsplit(
    const float* __restrict__ qk, const float* __restrict__ v,
    const float* __restrict__ q2, const float* __restrict__ k2,
    unsigned short* __restrict__ whl)
{
  const int e = blockIdx.x*256 + threadIdx.x;
  if (e >= 64512) return;
  const int row = e / 96, col = e - row*96;
  float f;
  if      (row <  192) f = qk[e];
  else if (row <  288) f = v [(row-192)*96+col];
  else if (row <  480) f = q2[(row-288)*96+col];
  else                 f = k2[(row-480)*96+col];
  rtn_split(f, &whl[e], &whl[110592 + e]);
}

// ---- compose CF = fqkv(288x96) @ proj(96x96) -> WHL rows 768..1055 ----
__global__ __launch_bounds__(256) void wcomp1(
    const float* __restrict__ fq, const float* __restrict__ pj,
    unsigned short* __restrict__ whl)
{
  const int e = blockIdx.x*256 + threadIdx.x;
  if (e >= 27648) return;
  const int row = e / 96, col = e - row*96;
  float s = 0.f;
  #pragma unroll 8
  for (int c = 0; c < 96; c++) s = fmaf(fq[row*96 + c], pj[c*96 + col], s);
  rtn_split(s, &whl[(768+row)*96 + col], &whl[110592 + (768+row)*96 + col]);
}

// ---- compose W2[b] = fproj(96x96) @ blockdiag(a2[b]) ----
__global__ __launch_bounds__(256) void wcomp2(
    const float* __restrict__ fp, const float* __restrict__ a2s,
    unsigned short* __restrict__ w2)
{
  const int e = blockIdx.x*256 + threadIdx.x;
  const int b = blockIdx.y;
  if (e >= 9216) return;
  const int co = e / 96, dg = e - co*96;
  const int h = dg / 12, d = dg - h*12;
  const float* ab = a2s + (((long)b*8 + h)*12)*12 + d;
  const float* fpb = fp + co*96 + h*12;
  float s = 0.f;
  #pragma unroll
  for (int c = 0; c < 12; c++) s = fmaf(fpb[c], ab[c*12], s);
  rtn_split(s, &w2[(long)b*9216 + e], &w2[18432 + (long)b*9216 + e]);
}

// ------- conv 1x1 via split-bf16 MFMA (3-way output split) -------
#define BLDS 104
__global__ __launch_bounds__(256) void conv1x1_mfma(
    const float* __restrict__ in, long in_bstride,
    const unsigned short* __restrict__ whl_hi, const unsigned short* __restrict__ whl_lo,
    long wbstride, int wrow0,
    float* __restrict__ out, long out_bstride,
    float* __restrict__ out2, long out2_bstride,
    float* __restrict__ out3, long out3_bstride,
    int ms1, int ms2, int mtiles, int mode)
{
  __shared__ unsigned short bhs[128*BLDS];
  __shared__ unsigned short bls[128*BLDS];
  const int t = threadIdx.x;
  const int p0 = blockIdx.x * 128;
  const int b = blockIdx.y;
  if (mode == 0) {
    #pragma unroll
    for (int it = 0; it < 6; it++) {
      const int idx = it*256 + t;
      const int g8 = idx >> 7;
      const int pix = idx & 127;
      const float* src = in + (long)b*in_bstride + (long)(g8*8)*HW + p0 + pix;
      unsigned hh[8], ll[8];
      #pragma unroll
      for (int j = 0; j < 8; j++) {
        float f = src[(long)j*HW];
        unsigned u = __float_as_uint(f);
        hh[j] = u >> 16;
        float lof = f - __uint_as_float(u & 0xFFFF0000u);
        __hip_bfloat16 lb = __float2bfloat16(lof);
        ll[j] = *(unsigned short*)&lb;
      }
      uint4 hv, lv;
      hv.x = hh[0]|(hh[1]<<16); hv.y = hh[2]|(hh[3]<<16);
      hv.z = hh[4]|(hh[5]<<16); hv.w = hh[6]|(hh[7]<<16);
      lv.x = ll[0]|(ll[1]<<16); lv.y = ll[2]|(ll[3]<<16);
      lv.z = ll[4]|(ll[5]<<16); lv.w = ll[6]|(ll[7]<<16);
      *(uint4*)(bhs + pix*BLDS + g8*8) = hv;
      *(uint4*)(bls + pix*BLDS + g8*8) = lv;
    }
  } else {
    const int pp = t >> 1, half = (t & 1)*48;
    const int p = p0 + pp;
    const int py = p >> 8, px = p & 255;
    const float* src = in + (long)b*in_bstride
        + ((long)((py & 63)*64 + (px & 63))*16 + ((py >> 6)*4 + (px >> 6)))*96 + half;
    #pragma unroll
    for (int j4 = 0; j4 < 12; j4++) {
      float4 v4 = *(const float4*)&src[j4*4];
      float fv[4] = {v4.x, v4.y, v4.z, v4.w};
      unsigned hh[4], ll[4];
      #pragma unroll
      for (int u4 = 0; u4 < 4; u4++) {
        unsigned u = __float_as_uint(fv[u4]);
        hh[u4] = u >> 16;
        float lof = fv[u4] - __uint_as_float(u & 0xFFFF0000u);
        __hip_bfloat16 lb = __float2bfloat16(lof);
        ll[u4] = *(unsigned short*)&lb;
      }
      uint2 hv, lv;
      hv.x = hh[0] | (hh[1] << 16); hv.y = hh[2] | (hh[3] << 16);
      lv.x = ll[0] | (ll[1] << 16); lv.y = ll[2] | (ll[3] << 16);
      *(uint2*)(bhs + pp*BLDS + half + j4*4) = hv;
      *(uint2*)(bls + pp*BLDS + half + j4*4) = lv;
    }
  }
  __syncthreads();
  const int lane = t & 63, w = t >> 6;
  const int fr = lane & 15, fk = lane >> 4;
  bf16x8 Bh[2][3], Bl[2][3];
  #pragma unroll
  for (int nt = 0; nt < 2; nt++)
    #pragma unroll
    for (int kt = 0; kt < 3; kt++) {
      const int pix = w*32 + nt*16 + fr;
      Bh[nt][kt] = *(const bf16x8*)(bhs + pix*BLDS + kt*32 + fk*8);
      Bl[nt][kt] = *(const bf16x8*)(bls + pix*BLDS + kt*32 + fk*8);
    }
  const long wb = (long)b*wbstride;
  for (int m = 0; m < mtiles; m++) {
    const long wbase = wb + (long)(wrow0 + m*16 + fr)*96 + fk*8;
    bf16x8 Ah[3], Al[3];
    #pragma unroll
    for (int kt = 0; kt < 3; kt++) {
      Ah[kt] = *(const bf16x8*)(whl_hi + wbase + kt*32);
      Al[kt] = *(const bf16x8*)(whl_lo + wbase + kt*32);
    }
    f32x4 acc[2] = {};
    #pragma unroll
    for (int nt = 0; nt < 2; nt++)
      #pragma unroll
      for (int kt = 0; kt < 3; kt++) {
        acc[nt] = __builtin_amdgcn_mfma_f32_16x16x32_bf16(Ah[kt], Bh[nt][kt], acc[nt], 0, 0, 0);
        acc[nt] = __builtin_amdgcn_mfma_f32_16x16x32_bf16(Ah[kt], Bl[nt][kt], acc[nt], 0, 0, 0);
        acc[nt] = __builtin_amdgcn_mfma_f32_16x16x32_bf16(Al[kt], Bh[nt][kt], acc[nt], 0, 0, 0);
      }
    int mo; float* dst;
    if (m < ms1)      { mo = m;       dst = out  + (long)b*out_bstride; }
    else if (m < ms2) { mo = m - ms1; dst = out2 + (long)b*out2_bstride; }
    else              { mo = m - ms2; dst = out3 + (long)b*out3_bstride; }
    dst += p0 + w*32;
    #pragma unroll
    for (int nt = 0; nt < 2; nt++)
      #pragma unroll
      for (int r = 0; r < 4; r++)
        dst[(long)(mo*16 + fk*4 + r)*HW + nt*16 + fr] = acc[nt][r];
  }
}

// -------- depthwise 3x3 pad 1, 4-wide vectorized --------
__global__ __launch_bounds__(256) void dw3x3v(
    const float* __restrict__ in, int inCH, const float* __restrict__ w,
    float* __restrict__ out, int outCH)
{
  const int t = threadIdx.x;
  const int p4 = blockIdx.x * 256 + t;
  const int ch = blockIdx.y, b = blockIdx.z;
  const int y = p4 >> 6, x0 = (p4 & 63) << 2;
  const float* ip = in + ((long)b*inCH + ch) * HW;
  const float* wp = w + ch*9;
  float a0 = 0.f, a1 = 0.f, a2 = 0.f, a3 = 0.f;
  #pragma unroll
  for (int dy = -1; dy <= 1; dy++) {
    const int yy = y + dy;
    if (yy < 0 || yy > 255) continue;
    const float* rp = ip + yy*256;
    const float4 c = *(const float4*)&rp[x0];
    const float left  = (x0 > 0)   ? rp[x0-1] : 0.f;
    const float right = (x0 < 252) ? rp[x0+4] : 0.f;
    const float w0 = wp[(dy+1)*3+0], w1 = wp[(dy+1)*3+1], w2 = wp[(dy+1)*3+2];
    a0 = fmaf(left, w0, a0); a0 = fmaf(c.x, w1, a0); a0 = fmaf(c.y, w2, a0);
    a1 = fmaf(c.x,  w0, a1); a1 = fmaf(c.y, w1, a1); a1 = fmaf(c.z, w2, a1);
    a2 = fmaf(c.y,  w0, a2); a2 = fmaf(c.z, w1, a2); a2 = fmaf(c.w, w2, a2);
    a3 = fmaf(c.z,  w0, a3); a3 = fmaf(c.w, w1, a3); a3 = fmaf(right, w2, a3);
  }
  float4 o; o.x = a0; o.y = a1; o.z = a2; o.w = a3;
  *(float4*)&out[((long)b*outCH + ch)*HW + y*256 + x0] = o;
}

// ------- depthwise 3x3 fused with v_s permutation (4-wide compute) ----
__global__ __launch_bounds__(256) void dw3x3_vs(
    const float* __restrict__ in, const float* __restrict__ w,
    float* __restrict__ vs)
{
  __shared__ float tile[96*65];
  const int t = threadIdx.x;
  const int gb = blockIdx.x;
  const int b = blockIdx.y;
  const int y = gb >> 2, xb = gb & 3;
  #pragma unroll
  for (int i = 0; i < 6; i++) {
    const int idx = i*256 + t;
    const int ci = idx >> 4, q = idx & 15;
    const int x0 = xb*64 + q*4;
    const float* ip = in + ((long)b*96 + ci) * HW;
    const float* wp = w + ci*9;
    float a0 = 0.f, a1 = 0.f, a2 = 0.f, a3 = 0.f;
    #pragma unroll
    for (int dy = -1; dy <= 1; dy++) {
      const int yy = y + dy;
      if (yy < 0 || yy > 255) continue;
      const float* rp = ip + yy*256;
      const float4 c = *(const float4*)&rp[x0];
      const float left  = (x0 > 0)   ? rp[x0-1] : 0.f;
      const float right = (x0 < 252) ? rp[x0+4] : 0.f;
      const float w0 = wp[(dy+1)*3+0], w1 = wp[(dy+1)*3+1], w2 = wp[(dy+1)*3+2];
      a0 = fmaf(left, w0, a0); a0 = fmaf(c.x, w1, a0); a0 = fmaf(c.y, w2, a0);
      a1 = fmaf(c.x,  w0, a1); a1 = fmaf(c.y, w1, a1); a1 = fmaf(c.z, w2, a1);
      a2 = fmaf(c.y,  w0, a2); a2 = fmaf(c.z, w1, a2); a2 = fmaf(c.w, w2, a2);
      a3 = fmaf(c.z,  w0, a3); a3 = fmaf(c.w, w1, a3); a3 = fmaf(right, w2, a3);
    }
    const int xl = q*4;
    tile[ci*65 + xl    ] = a0;
    tile[ci*65 + xl + 1] = a1;
    tile[ci*65 + xl + 2] = a2;
    tile[ci*65 + xl + 3] = a3;
  }
  __syncthreads();
  const int blk = (y >> 6)*4 + xb;
  float* obase = vs + ((long)b*4096 + (long)(y & 63)*64) * 1536 + blk*96;
  #pragma unroll
  for (int i = 0; i < 24; i++) {
    const int idx = i*256 + t;
    const int nl = idx / 96, ci = idx % 96;
    obase[(long)nl*1536 + ci] = tile[ci*65 + nl];
  }
}

// ---- depthwise 4x4 stride 4 pad 1 (256->64), 4-wide vectorized ----
__global__ __launch_bounds__(256) void dw4x4s4v(
    const float* __restrict__ in, const float* __restrict__ w,
    float* __restrict__ out)
{
  const int t = threadIdx.x;
  const int p = blockIdx.x*256 + t;
  const int ch = blockIdx.y, b = blockIdx.z;
  const int oy = p >> 4, qx = p & 15;
  const int x0 = qx*16;
  const float* ip = in + (long)(b*192 + ch) * HW;
  const float* wp = w + ch*16;
  float a0 = 0.f, a1 = 0.f, a2 = 0.f, a3 = 0.f;
  #pragma unroll
  for (int ty = 0; ty < 4; ty++) {
    const int iy = 4*oy + ty - 1;
    if (iy < 0 || iy > 255) continue;
    const float* rp = ip + iy*256;
    float r[17];
    r[0] = (x0 > 0) ? rp[x0-1] : 0.f;
    #pragma unroll
    for (int k = 0; k < 4; k++) {
      float4 v4 = *(const float4*)&rp[x0 + k*4];
      r[1+k*4+0]=v4.x; r[1+k*4+1]=v4.y; r[1+k*4+2]=v4.z; r[1+k*4+3]=v4.w;
    }
    const float w0=wp[ty*4+0], w1=wp[ty*4+1], w2=wp[ty*4+2], w3=wp[ty*4+3];
    a0=fmaf(r[ 0],w0,a0); a0=fmaf(r[ 1],w1,a0); a0=fmaf(r[ 2],w2,a0); a0=fmaf(r[ 3],w3,a0);
    a1=fmaf(r[ 4],w0,a1); a1=fmaf(r[ 5],w1,a1); a1=fmaf(r[ 6],w2,a1); a1=fmaf(r[ 7],w3,a1);
    a2=fmaf(r[ 8],w0,a2); a2=fmaf(r[ 9],w1,a2); a2=fmaf(r[10],w2,a2); a2=fmaf(r[11],w3,a2);
    a3=fmaf(r[12],w0,a3); a3=fmaf(r[13],w1,a3); a3=fmaf(r[14],w2,a3); a3=fmaf(r[15],w3,a3);
  }
  float4 o; o.x=a0; o.y=a1; o.z=a2; o.w=a3;
  *(float4*)&out[(long)(b*192 + ch)*4096 + oy*64 + qx*4] = o;
}

// ---------------- l2 norm over 192 channels + transpose (both q & k) ----
__global__ __launch_bounds__(256) void l2n192(
    const float* __restrict__ inA, float* __restrict__ outA,
    const float* __restrict__ inB, float* __restrict__ outB)
{
  const int t = threadIdx.x;
  const int wid = t >> 6, lane = t & 63;
  const int gw2 = blockIdx.x * 4 + wid;
  const int sel = gw2 >> 13;
  const int gw = gw2 & 8191;
  const int b = gw >> 12, n = gw & 4095;
  const float* ip = (sel ? inB : inA) + (long)b * 786432;
  float v0 = ip[(long)(lane      ) * 4096 + n];
  float v1 = ip[(long)(lane +  64) * 4096 + n];
  float v2 = ip[(long)(lane + 128) * 4096 + n];
  float ss = v0*v0 + v1*v1 + v2*v2;
  #pragma unroll
  for (int s = 1; s < 64; s <<= 1) ss += __shfl_xor(ss, s, 64);
  float nrm = fmaxf(sqrtf(ss), 1e-12f);
  float* op = (sel ? outB : outA) + ((long)b*4096 + n) * 192;
  op[lane      ] = v0 / nrm;
  op[lane +  64] = v1 / nrm;
  op[lane + 128] = v2 / nrm;
}

// ------- split fp32 -> (hi,lo) bf16 planes; both batches -------
__global__ __launch_bounds__(256) void bf16split(
    const float* __restrict__ in, unsigned short* __restrict__ outp)
{
  const int i = blockIdx.x * 256 + threadIdx.x;
  const int n = i / 192, k = i % 192;
  float f = in[i];
  unsigned short h, l;
  rtn_split(f, &h, &l);
  outp[(long)n*384 + k]       = h;
  outp[(long)n*384 + 192 + k] = l;
}

// ------- attention QK^T via split-bf16 MFMA (both batches) -------
#define LDSROW 40
__global__ __launch_bounds__(256) void attn_qk_mfma(
    const unsigned short* __restrict__ Qsp, const unsigned short* __restrict__ Ksp,
    float* __restrict__ attn, const float* __restrict__ tp)
{
  __shared__ unsigned short qs[256*LDSROW];
  __shared__ unsigned short ks[256*LDSROW];
  const int t = threadIdx.x;
  const int lane = t & 63, w = t >> 6;
  const int n0 = blockIdx.x * 128;
  const int m0 = blockIdx.y * 128;
  const int bb = blockIdx.z;
  const unsigned short* Qb = Qsp + (long)bb*1572864;
  const unsigned short* Kb = Ksp + (long)bb*1572864;
  float* attb = attn + (long)bb*16777216;
  const int wr = (w >> 1) * 64, wc = (w & 1) * 64;
  f32x4 acc[4][4] = {};
  const int srow = t & 127;
  const int shl  = t >> 7;
  const unsigned short* qsrc = Qb + (long)(n0 + srow) * 384 + shl * 192;
  const unsigned short* ksrc = Kb + (long)(m0 + srow) * 384 + shl * 192;
  unsigned short* qdst = qs + (shl*128 + srow) * LDSROW;
  unsigned short* kdst = ks + (shl*128 + srow) * LDSROW;
  const int fr = lane & 15;
  const int fk = lane >> 4;
  for (int s = 0; s < 6; s++) {
    __syncthreads();
    #pragma unroll
    for (int j = 0; j < 4; j++) {
      *(bf16x8*)(qdst + j*8) = *(const bf16x8*)(qsrc + s*32 + j*8);
      *(bf16x8*)(kdst + j*8) = *(const bf16x8*)(ksrc + s*32 + j*8);
    }
    __syncthreads();
    bf16x8 ah[4], al[4], bh[4], bl[4];
    #pragma unroll
    for (int i = 0; i < 4; i++) {
      ah[i] = *(const bf16x8*)(qs + (      wr + i*16 + fr) * LDSROW + fk*8);
      al[i] = *(const bf16x8*)(qs + (128 + wr + i*16 + fr) * LDSROW + fk*8);
      bh[i] = *(const bf16x8*)(ks + (      wc + i*16 + fr) * LDSROW + fk*8);
      bl[i] = *(const bf16x8*)(ks + (128 + wc + i*16 + fr) * LDSROW + fk*8);
    }
    #pragma unroll
    for (int i = 0; i < 4; i++)
      #pragma unroll
      for (int j = 0; j < 4; j++) {
        acc[i][j] = __builtin_amdgcn_mfma_f32_16x16x32_bf16(ah[i], bh[j], acc[i][j], 0, 0, 0);
        acc[i][j] = __builtin_amdgcn_mfma_f32_16x16x32_bf16(ah[i], bl[j], acc[i][j], 0, 0, 0);
        acc[i][j] = __builtin_amdgcn_mfma_f32_16x16x32_bf16(al[i], bh[j], acc[i][j], 0, 0, 0);
      }
  }
  const float temp = tp[0];
  #pragma unroll
  for (int i = 0; i < 4; i++)
    #pragma unroll
    for (int j = 0; j < 4; j++)
      #pragma unroll
      for (int r = 0; r < 4; r++) {
        const int nn = n0 + wr + i*16 + (lane >> 4)*4 + r;
        const int mm = m0 + wc + j*16 + (lane & 15);
        attb[(long)nn*4096 + mm] = acc[i][j][r] * temp;
      }
}

// ------- top-5 + local mask + softmax + sparse out -------
// R20: R17 structure (256 thr) + wave-butterfly top-5 merge (1 barrier).
#define CAP 128
__global__ __launch_bounds__(256) void attn_out_k(
    const float* __restrict__ attn, const float* __restrict__ vs,
    float* __restrict__ outr)
{
  __shared__ float wtop[4*5];
  __shared__ int   lm[CAP];
  __shared__ float lw[CAP];
  __shared__ float ses[CAP];
  __shared__ float redf[8];
  __shared__ int   wsum[4];
  const int t = threadIdx.x;
  const int bid = blockIdx.x;
  const int n = ((bid & 7) << 9) | (bid >> 3);   // XCD-chunked rows
  const int bb = blockIdx.y;
  const float* ar = attn + (long)bb*16777216 + (long)n * 4096;
  const float* vsb = vs + (long)bb*6291456;
  float av[16];
  float cur[5];
  {
    float t0=-INFINITY,t1=-INFINITY,t2=-INFINITY,t3=-INFINITY,t4=-INFINITY;
    #pragma unroll
    for (int q = 0; q < 4; q++) {
      float4 v4 = *(const float4*)&ar[t*16 + q*4];
      float vv[4] = {v4.x, v4.y, v4.z, v4.w};
      #pragma unroll
      for (int u = 0; u < 4; u++) {
        float v = vv[u];
        av[q*4+u] = v;
        if (v > t4) {
          if (v > t0)      { t4=t3; t3=t2; t2=t1; t1=t0; t0=v; }
          else if (v > t1) { t4=t3; t3=t2; t2=t1; t1=v; }
          else if (v > t2) { t4=t3; t3=t2; t2=v; }
          else if (v > t3) { t4=t3; t3=v; }
          else             { t4=v; }
        }
      }
    }
    cur[0]=t0; cur[1]=t1; cur[2]=t2; cur[3]=t3; cur[4]=t4;
  }
  // wave butterfly merge: after 6 rounds every lane holds wave-top5
  #pragma unroll
  for (int s = 1; s < 64; s <<= 1) {
    float ot[5];
    #pragma unroll
    for (int r = 0; r < 5; r++) ot[r] = __shfl_xor(cur[r], s, 64);
    float m[5]; int i = 0, j = 0;
    #pragma unroll
    for (int k = 0; k < 5; k++) {
      float a = cur[i], o = ot[j];
      if (a >= o) { m[k] = a; i++; } else { m[k] = o; j++; }
    }
    #pragma unroll
    for (int k = 0; k < 5; k++) cur[k] = m[k];
  }
  if ((t & 63) == 0) {
    #pragma unroll
    for (int r = 0; r < 5; r++) wtop[(t >> 6)*5 + r] = cur[r];
  }
  __syncthreads();
  // every thread merges the 4 wave lists (registers, redundant but cheap)
  float kth;
  {
    int idx0 = 0, idx1 = 0, idx2 = 0, idx3 = 0;
    float last = -INFINITY;
    #pragma unroll
    for (int k = 0; k < 5; k++) {
      float c0 = wtop[0*5 + idx0], c1 = wtop[1*5 + idx1];
      float c2 = wtop[2*5 + idx2], c3 = wtop[3*5 + idx3];
      float mx01 = fmaxf(c0, c1), mx23 = fmaxf(c2, c3);
      float mx = fmaxf(mx01, mx23);
      if (mx == c0 && mx01 >= mx23)      idx0++;
      else if (mx == c1 && mx01 >= mx23) idx1++;
      else if (mx == c2)                 idx2++;
      else                               idx3++;
      last = mx;
    }
    kth = last;
  }
  const int y = n >> 6, x = n & 63;
  int myc = 0;
  float wmax = -INFINITY;
  float fvv[16];
  #pragma unroll
  for (int k = 0; k < 16; k++) {
    const int m = t*16 + k;
    float a = av[k];
    int c = ((a >= kth) ? 1 : 0) +
            (((iabs_(y - (m >> 6)) + iabs_(x - (m & 63))) <= 4) ? 1 : 0);
    float wv = a * (float)c;
    fvv[k] = wv;
    if (wv != 0.0f) { myc++; wmax = fmaxf(wmax, wv); }
  }
  int inc = myc;
  #pragma unroll
  for (int s = 1; s < 64; s <<= 1) {
    int v = __shfl_up(inc, s, 64);
    if ((t & 63) >= s) inc += v;
  }
  if ((t & 63) == 63) wsum[t >> 6] = inc;
  __syncthreads();
  int pre = 0;
  #pragma unroll
  for (int wj = 0; wj < 4; wj++) pre += (wj < (t >> 6)) ? wsum[wj] : 0;
  const int base = pre + inc - myc;
  const int cnt = wsum[0] + wsum[1] + wsum[2] + wsum[3];
  {
    int idx = base;
    #pragma unroll
    for (int k = 0; k < 16; k++) {
      float wv = fvv[k];
      if (wv != 0.0f && idx < CAP) { lm[idx] = t*16 + k; lw[idx] = wv; idx++; }
    }
  }
  #pragma unroll
  for (int s = 1; s < 64; s <<= 1) wmax = fmaxf(wmax, __shfl_xor(wmax, s, 64));
  if ((t & 63) == 0) redf[t >> 6] = wmax;
  __syncthreads();
  const float gmax = fmaxf(fmaxf(redf[0], redf[1]), fmaxf(redf[2], redf[3]));
  __syncthreads();
  if (t < CAP) ses[t] = (t < cnt) ? expf(lw[t] - gmax) : 0.f;
  __syncthreads();
  float ps = (t < cnt && t < CAP) ? ses[t] : 0.f;
  #pragma unroll
  for (int s = 1; s < 64; s <<= 1) ps += __shfl_xor(ps, s, 64);
  if ((t & 63) == 0) redf[4 + (t >> 6)] = ps;
  __syncthreads();
  const float S = redf[4] + redf[5] + redf[6] + redf[7];
  const float invS = 1.0f / S;
  // PV: thread owns out[t*4..t*4+3]; waves 0-1 also [1024+t*4..)
  float a0 = 0.f, a1 = 0.f, a2 = 0.f, a3 = 0.f;
  float b0 = 0.f, b1 = 0.f, b2 = 0.f, b3 = 0.f;
  const int ecnt = (cnt < CAP) ? cnt : CAP;
  const bool lohalf = (t < 128);
  for (int e = 0; e < ecnt; e++) {
    float se = ses[e];
    const float* vr = vsb + (long)lm[e] * 1536;
    float4 v4 = *(const float4*)&vr[t*4];
    a0 = fmaf(se, v4.x, a0);
    a1 = fmaf(se, v4.y, a1);
    a2 = fmaf(se, v4.z, a2);
    a3 = fmaf(se, v4.w, a3);
    if (lohalf) {
      float4 w4 = *(const float4*)&vr[1024 + t*4];
      b0 = fmaf(se, w4.x, b0);
      b1 = fmaf(se, w4.y, b1);
      b2 = fmaf(se, w4.z, b2);
      b3 = fmaf(se, w4.w, b3);
    }
  }
  float* orow = outr + (long)bb*6291456 + (long)n * 1536;
  float4 o; o.x = a0*invS; o.y = a1*invS; o.z = a2*invS; o.w = a3*invS;
  *(float4*)&orow[t*4] = o;
  if (lohalf) {
    float4 o2; o2.x = b0*invS; o2.y = b1*invS; o2.z = b2*invS; o2.w = b3*invS;
    *(float4*)&orow[1024 + t*4] = o2;
  }
}

// ------- per-channel l2 norm over 65536 (fhr k2); in-place safe -------
__global__ __launch_bounds__(1024) void l2n_sp(
    const float* __restrict__ in, float* __restrict__ out)
{
  const int ch = blockIdx.x, b = blockIdx.y, t = threadIdx.x;
  const float* ip = in + ((long)b*96 + ch) * HW;
  float ss = 0.f;
  for (int i = t; i < 65536; i += 1024) { float v = ip[i]; ss = fmaf(v, v, ss); }
  __shared__ float red[16];
  #pragma unroll
  for (int s = 1; s < 64; s <<= 1) ss += __shfl_xor(ss, s, 64);
  if ((t & 63) == 0) red[t >> 6] = ss;
  __syncthreads();
  if (t == 0) {
    float s2 = 0.f;
    for (int i = 0; i < 16; i++) s2 += red[i];
    red[0] = fmaxf(sqrtf(s2), 1e-12f);
  }
  __syncthreads();
  const float nrm = red[0];
  float* op = out + ((long)b*96 + ch) * HW;
  for (int i = t; i < 65536; i += 1024) op[i] = ip[i] / nrm;
}

// -------- a2 stage 1: raw-q Gram + q sum-of-squares partials ----------
#define A2_NCH 16
__global__ __launch_bounds__(256) void a2_part(
    const float* __restrict__ q2n, const float* __restrict__ k2n,
    float* __restrict__ part, float* __restrict__ qqpart)
{
  __shared__ float sh[24*260];
  const int t = threadIdx.x;
  const int ch = blockIdx.x, h = blockIdx.y, b = blockIdx.z;
  const long base = ((long)b*96 + h*12) * HW + ch*4096;
  const int c = t / 12, d = t - (t/12)*12;
  float acc = 0.f;
  float qq = 0.f;
  for (int sub = 0; sub < 16; sub++) {
    __syncthreads();
    #pragma unroll
    for (int j = 0; j < 6; j++) {
      const int v = j*256 + t;
      const int row = v >> 6;
      const int col4 = v & 63;
      const float* src = (row < 12)
        ? q2n + base + (long)row*HW + sub*256 + col4*4
        : k2n + base + (long)(row-12)*HW + sub*256 + col4*4;
      *(float4*)&sh[row*260 + col4*4] = *(const float4*)src;
    }
    __syncthreads();
    if (t < 144) {
      const float* qr = &sh[c*260];
      const float* kr = &sh[(12+d)*260];
      #pragma unroll
      for (int i4 = 0; i4 < 64; i4++) {
        float4 qv = *(const float4*)&qr[i4*4];
        float4 kv = *(const float4*)&kr[i4*4];
        acc = fmaf(qv.x, kv.x, acc);
        acc = fmaf(qv.y, kv.y, acc);
        acc = fmaf(qv.z, kv.z, acc);
        acc = fmaf(qv.w, kv.w, acc);
      }
    } else if (t < 156) {
      const float* qr = &sh[(t-144)*260];
      #pragma unroll
      for (int i4 = 0; i4 < 64; i4++) {
        float4 qv = *(const float4*)&qr[i4*4];
        qq = fmaf(qv.x, qv.x, qq);
        qq = fmaf(qv.y, qv.y, qq);
        qq = fmaf(qv.z, qv.z, qq);
        qq = fmaf(qv.w, qv.w, qq);
      }
    }
  }
  if (t < 144)
    part[(((long)b*8 + h)*A2_NCH + ch)*144 + t] = acc;
  else if (t < 156)
    qqpart[(((long)b*8 + h)*A2_NCH + ch)*12 + (t-144)] = qq;
}

// -------- a2 stage 2: fold q-normalization --------
__global__ __launch_bounds__(256) void a2_fin(
    const float* __restrict__ part, const float* __restrict__ qqpart,
    const float* __restrict__ temp, float* __restrict__ a2s)
{
  __shared__ float m[144];
  __shared__ float qn[12];
  const int t = threadIdx.x;
  const int h = blockIdx.x, b = blockIdx.y;
  if (t < 144) {
    float s = 0.f;
    const float* pp = part + (((long)b*8 + h)*A2_NCH)*144 + t;
    #pragma unroll
    for (int ch = 0; ch < A2_NCH; ch++) s += pp[ch*144];
    m[t] = s;
  } else if (t < 156) {
    float s = 0.f;
    const float* pp = qqpart + (((long)b*8 + h)*A2_NCH)*12 + (t-144);
    #pragma unroll
    for (int ch = 0; ch < A2_NCH; ch++) s += pp[ch*12];
    qn[t-144] = fmaxf(sqrtf(s), 1e-12f);
  }
  __syncthreads();
  if (t < 12) {
    const float tv = temp[h];
    const float scale = tv / qn[t];
    float mx = -INFINITY;
    float a[12];
    #pragma unroll
    for (int d = 0; d < 12; d++) { a[d] = m[t*12+d] * scale; mx = fmaxf(mx, a[d]); }
    float e[12], sum = 0.f;
    #pragma unroll
    for (int d = 0; d < 12; d++) { e[d] = expf(a[d]-mx); sum += e[d]; }
    float inv = 1.0f/sum;
    float* op = a2s + (((long)b*8 + h)*12 + t)*12;
    #pragma unroll
    for (int d = 0; d < 12; d++) op[d] = e[d]*inv;
  }
}

extern "C" void kernel_launch(void* const* d_in, const int* in_sizes, int n_in,
                              void* d_out, int out_size, void* d_ws, size_t ws_size,
                              hipStream_t stream) {
  const float* x        = (const float*)d_in[0];
  const float* qk_w     = (const float*)d_in[1];
  const float* qk_dw    = (const float*)d_in[2];
  const float* v_w      = (const float*)d_in[3];
  const float* v_dw     = (const float*)d_in[4];
  const float* k2_w     = (const float*)d_in[5];
  const float* k2_dw    = (const float*)d_in[6];
  const float* q2_w     = (const float*)d_in[7];
  const float* q2_dw    = (const float*)d_in[8];
  const float* proj_w   = (const float*)d_in[9];
  const float* sab_temp = (const float*)d_in[10];
  const float* fqkv_w   = (const float*)d_in[11];
  const float* fqkv_dw  = (const float*)d_in[12];
  const float* fproj_w  = (const float*)d_in[13];
  const float* fhr_temp = (const float*)d_in[14];
  float* out = (float*)d_out;
  float* ws  = (float*)d_ws;

  float* O2  = out;
  float* KS  = out + 12582912;
  float* VS  = out + 14155776;
  float* K2N = out + 26738688;
  float* V2  = out + 39321600;

  float* A0   = ws;
  float* A1   = ws + 25165824;
  float* QD   = ws + 50331648;
  float* KD   = ws + 51904512;
  float* QN   = ws + 53477376;
  float* A2S  = ws + 55050240;
  float* PART = ws + 55052544;
  unsigned short* WHL = (unsigned short*)QN;
  float* ATT  = ws;
  unsigned short* QSP = (unsigned short*)(ws + 33554432);
  unsigned short* KSP = (unsigned short*)(ws + 35127296);
  float* AOUT = ws + 37748736;
  float* P1  = ws;
  float* P2  = ws + 12582912;
  float* P3  = ws + 25165824;
  float* ALNQ = P2;
  float* QQP = QD;
  unsigned short* W2HL = (unsigned short*)PART;

  dim3 b256(256), b1024(1024);

  wsplit<<<dim3(252), b256, 0, stream>>>(qk_w, v_w, q2_w, k2_w, WHL);
  conv1x1_mfma<<<dim3(512,2), b256, 0, stream>>>(
      x, 96L*HW, WHL, WHL+110592, 0, 0,
      A0, 192L*HW, A1, 96L*HW, A1, 96L*HW, 12, 18, 18, 0);
  dw3x3_vs<<<dim3(1024,2), b256, 0, stream>>>(A1, v_dw, VS);
  dw3x3v<<<dim3(64,192,2), b256, 0, stream>>>(A0, 192, qk_dw, A1, 192);
  conv1x1_mfma<<<dim3(512,2), b256, 0, stream>>>(
      A1, 192L*HW, WHL, WHL+110592, 0, 288,
      A0, 192L*HW, A0, 192L*HW, A0, 192L*HW, 12, 12, 12, 0);
  dw4x4s4v<<<dim3(4,192,2), b256, 0, stream>>>(A0, q2_dw, QD);
  conv1x1_mfma<<<dim3(512,2), b256, 0, stream>>>(
      A1 + 96L*HW, 192L*HW, WHL, WHL+110592, 0, 480,
      A0, 192L*HW, A0, 192L*HW, A0, 192L*HW, 12, 12, 12, 0);
  dw4x4s4v<<<dim3(4,192,2), b256, 0, stream>>>(A0, k2_dw, KD);
  l2n192<<<dim3(4096), b256, 0, stream>>>(QD, QN, KD, KS);
  bf16split<<<dim3(6144), b256, 0, stream>>>(QN, QSP);
  bf16split<<<dim3(6144), b256, 0, stream>>>(KS, KSP);
  attn_qk_mfma<<<dim3(32,32,2), b256, 0, stream>>>(QSP, KSP, ATT, sab_temp);
  attn_out_k<<<dim3(4096,2), b256, 0, stream>>>(ATT, VS, AOUT);
  wcomp1<<<dim3(108), b256, 0, stream>>>(fqkv_w, proj_w, WHL);
  conv1x1_mfma<<<dim3(512,2), b256, 0, stream>>>(
      AOUT, 6291456L, WHL, WHL+110592, 0, 768,
      P1, 96L*HW, P2, 96L*HW, P3, 96L*HW, 6, 12, 18, 1);
  dw3x3v<<<dim3(64,96,2), b256, 0, stream>>>(P2, 96, fqkv_dw +  864, K2N, 96);
  dw3x3v<<<dim3(64,96,2), b256, 0, stream>>>(P3, 96, fqkv_dw + 1728, V2,  96);
  dw3x3v<<<dim3(64,96,2), b256, 0, stream>>>(P1, 96, fqkv_dw,        ALNQ, 96);
  l2n_sp<<<dim3(96,2), b1024, 0, stream>>>(K2N, K2N);
  a2_part<<<dim3(A2_NCH,8,2), b256, 0, stream>>>(ALNQ, K2N, PART, QQP);
  a2_fin<<<dim3(8,2), b256, 0, stream>>>(PART, QQP, fhr_temp, A2S);
  wcomp2<<<dim3(36,2), b256, 0, stream>>>(fproj_w, A2S, W2HL);
  conv1x1_mfma<<<dim3(512,2), b256, 0, stream>>>(
      V2, 96L*HW, W2HL, W2HL+18432, 9216, 0,
      O2, 96L*HW, O2, 96L*HW, O2, 96L*HW, 6, 6, 6, 0);
}